// Round 7
// baseline (478.215 us; speedup 1.0000x reference)
//
#include <hip/hip_runtime.h>
#include <hip/hip_bf16.h>
#include <stdint.h>
#include <math.h>

// TreeLSTM on MI355X — v7: v6 (hand-scheduled K-loop, AITER-style waits) with
// the ds_read byte-offset bug fixed (B step stride is 1024 BYTES, not 512).

typedef __bf16 bf16x8 __attribute__((ext_vector_type(8)));
typedef float  f32x4  __attribute__((ext_vector_type(4)));
typedef int    i32x4  __attribute__((ext_vector_type(4)));
typedef __attribute__((address_space(3))) __bf16 lds_bf16;

__device__ __forceinline__ float sigf(float x) { return 1.f / (1.f + __expf(-x)); }
__device__ __forceinline__ float tanhfast(float x) {
    return 1.f - 2.f / (__expf(2.f * x) + 1.f);   // stable at |x| large
}

__global__ void xg_prep(const float* __restrict__ emb, const float* __restrict__ W,
                        const float* __restrict__ bW, float* __restrict__ xg) {
    int g = blockIdx.x >> 6, v = blockIdx.x & 63, k = threadIdx.x;
    __shared__ float e[256];
    e[k] = emb[v * 256 + k];
    __syncthreads();
    float s = bW[g * 256 + k];
    const float* Wg = W + g * 65536 + k;
#pragma unroll 4
    for (int i = 0; i < 256; i++) s += e[i] * Wg[i * 256];
    xg[(g * 64 + v) * 256 + k] = s;
}

// Pack U into MFMA-fragment order: BtP[g][ct][ks][lane][e], e<8
// value = Ucat[g][col=ct*16+(lane&15)][k=ks*32+(lane>>4)*8+e]
// Ucat[g][col][k] = U[g][k<256?0:1][k&255][col]
__global__ void bt_prep(const float* __restrict__ U, __bf16* __restrict__ BtP) {
    int t = blockIdx.x * 256 + threadIdx.x;     // < 81920
    int g    = t >> 14;
    int r    = t & 16383;
    int ct   = r >> 10;
    int ks   = (r >> 6) & 15;
    int lane = t & 63;
    int lr = lane & 15, q = lane >> 4;
    int col = ct * 16 + lr;
    int kbase = ks * 32 + q * 8;
    bf16x8 v8;
#pragma unroll
    for (int e = 0; e < 8; e++) {
        int k = kbase + e;
        int s = k >> 8, kk = k & 255;
        v8[e] = (__bf16)U[((g * 2 + s) * 256 + kk) * 256 + col];
    }
    *(bf16x8*)(BtP + (long)t * 8) = v8;
}

__global__ void leaf_kernel(const int* __restrict__ ids, const float* __restrict__ xg,
                            __bf16* __restrict__ h, __bf16* __restrict__ c) {
    int col = threadIdx.x;                 // 0..255
    int r0 = blockIdx.x * 32;              // 2048 blocks x 32 rows
    for (int r = r0; r < r0 + 32; r++) {
        int b = r >> 10, j = r & 1023;
        int id = ids[b * 2046 + 1022 + j];
        float x1 = xg[(64  + id) * 256 + col];
        float x2 = xg[(128 + id) * 256 + col];
        float x3 = xg[(192 + id) * 256 + col];
        float ig = sigf(x1);
        float og = sigf(x2);
        float ug = tanhfast(x3);
        float cv = ig * ug;
        float hv = og * tanhfast(cv);
        h[r * 256 + col] = (__bf16)hv;
        c[r * 256 + col] = (__bf16)cv;
    }
}

// ---- hand-scheduled K-loop machinery ----
#define GLA(dst, base, OFFL) \
    asm volatile("global_load_dwordx4 %0, %1, off offset:" OFFL \
                 : "=v"(dst) : "v"(base))
#define DSR(dst, base, OFFL) \
    asm volatile("ds_read_b128 %0, %1 offset:" OFFL \
                 : "=v"(dst) : "v"(base))

#define STEPA(al, OFFL) \
    GLA(af[al][0], ApB0, OFFL); GLA(af[al][1], ApB1, OFFL); \
    GLA(af[al][2], ApB2, OFFL); GLA(af[al][3], ApB3, OFFL);
#define STEPB(bl, OFFL) \
    DSR(bb[bl][0], dsb0, OFFL); DSR(bb[bl][1], dsb1, OFFL); \
    DSR(bb[bl][2], dsb2, OFFL); DSR(bb[bl][3], dsb3, OFFL); \
    DSR(bb[bl][4], dsb4, OFFL);

// Wait claims ("+v") the step's buffers so MFMAs can't be hoisted above it.
#define WAITK(WSTR, ac, bc) \
    asm volatile(WSTR : "+v"(af[ac][0]), "+v"(af[ac][1]), "+v"(af[ac][2]), \
                        "+v"(af[ac][3]), "+v"(bb[bc][0]), "+v"(bb[bc][1]), \
                        "+v"(bb[bc][2]), "+v"(bb[bc][3]), "+v"(bb[bc][4]))

#define MFMA20(ac, bc) \
    for (int g2 = 0; g2 < 5; g2++) \
        for (int mt = 0; mt < 4; mt++) \
            acc[g2][mt] = __builtin_amdgcn_mfma_f32_16x16x32_bf16( \
                __builtin_bit_cast(bf16x8, af[ac][mt]), \
                __builtin_bit_cast(bf16x8, bb[bc][g2]), acc[g2][mt], 0, 0, 0);

#define KSTEP(ac, bc, al, AOFF, bl, BOFF) \
    STEPA(al, AOFF) STEPB(bl, BOFF) \
    WAITK("s_waitcnt vmcnt(8) lgkmcnt(5)", ac, bc); MFMA20(ac, bc)
#define KSTEP_NA(ac, bc, bl, BOFF) \
    STEPB(bl, BOFF) \
    WAITK("s_waitcnt vmcnt(4) lgkmcnt(5)", ac, bc); MFMA20(ac, bc)
#define KSTEP_LAST(ac, bc) \
    WAITK("s_waitcnt vmcnt(0) lgkmcnt(0)", ac, bc); MFMA20(ac, bc)

// Block = 512 thr = 8 waves x 64 rows; one ct (16 cols), all 5 gates.
__global__ __launch_bounds__(512, 2) void level_kernel(
    const __bf16* __restrict__ A, const __bf16* __restrict__ Cprev,
    const __bf16* __restrict__ BtP, const float* __restrict__ xg,
    const int* __restrict__ ids, __bf16* __restrict__ h_out,
    __bf16* __restrict__ c_out, float* __restrict__ rh_out, int lev, int M) {
    __shared__ __bf16 Blds[5 * 16 * 512];     // 80 KB
    const int tid  = threadIdx.x;
    const int wave = tid >> 6;
    const int lane = tid & 63;
    const int lr = lane & 15, q = lane >> 4;
    const int ct = blockIdx.y;
    const long wrow = (long)blockIdx.x * 512 + wave * 64;
    const bool active = (wrow < M);

    // ---- Stage B-slice -> LDS, fragment order (conflict-free 16B/lane). ----
#pragma unroll
    for (int i = 0; i < 10; i++) {
        int c = tid + i * 512;
        int g = c >> 10;
        int r = c & 1023;
        i32x4 v = *(const i32x4*)(BtP + (long)(g * 16 + ct) * 8192 + r * 8);
        *(i32x4*)(&Blds[g * 8192 + r * 8]) = v;
    }
    __syncthreads();

    if (active) {
        // Base registers: all per-step addressing is an immediate offset.
        const __bf16* Abase = A + (wrow + lr) * 512 + q * 8;
        const __bf16* ApB0 = Abase;
        const __bf16* ApB1 = Abase + 8192;
        const __bf16* ApB2 = Abase + 16384;
        const __bf16* ApB3 = Abase + 24576;
        lds_bf16* dsbase = (lds_bf16*)&Blds[lane * 8];
        lds_bf16* dsb0 = dsbase;
        lds_bf16* dsb1 = dsbase + 8192;
        lds_bf16* dsb2 = dsbase + 16384;
        lds_bf16* dsb3 = dsbase + 24576;
        lds_bf16* dsb4 = dsbase + 32768;

        f32x4 acc[5][4];
#pragma unroll
        for (int g2 = 0; g2 < 5; g2++)
#pragma unroll
            for (int mt = 0; mt < 4; mt++) acc[g2][mt] = (f32x4){0.f, 0.f, 0.f, 0.f};

        i32x4 af[3][4], bb[2][5];
        // Prologue: A(0) @0, A(1) @64B, B(0) @0.
        STEPA(0, "0") STEPA(1, "64") STEPB(0, "0")
        // Step s: issue A(s+2) @ (s+2)*64 B, B(s+1) @ (s+1)*1024 B.
        KSTEP(0, 0, 2, "128", 1, "1024")
        KSTEP(1, 1, 0, "192", 0, "2048")
        KSTEP(2, 0, 1, "256", 1, "3072")
        KSTEP(0, 1, 2, "320", 0, "4096")
        KSTEP(1, 0, 0, "384", 1, "5120")
        KSTEP(2, 1, 1, "448", 0, "6144")
        KSTEP(0, 0, 2, "512", 1, "7168")
        KSTEP(1, 1, 0, "576", 0, "8192")
        KSTEP(2, 0, 1, "640", 1, "9216")
        KSTEP(0, 1, 2, "704", 0, "10240")
        KSTEP(1, 0, 0, "768", 1, "11264")
        KSTEP(2, 1, 1, "832", 0, "12288")
        KSTEP(0, 0, 2, "896", 1, "13312")
        KSTEP(1, 1, 0, "960", 0, "14336")
        KSTEP_NA(2, 0, 1, "15360")
        KSTEP_LAST(0, 1)

        // ---- Epilogue (loads here; latency amortizes once per wave). ----
        const int n = 1 << lev;
        const int gcol = ct * 16 + lr;
        int idv[4][4];
        float clv[4][4], crv[4][4];
#pragma unroll
        for (int mt = 0; mt < 4; mt++)
#pragma unroll
            for (int v = 0; v < 4; v++) {
                long grow = wrow + mt * 16 + q * 4 + v;
                int b = (int)(grow >> lev);
                int j = (int)(grow & (n - 1));
                idv[mt][v] = ids[b * 2046 + (n - 2) + j];
                clv[mt][v] = (float)Cprev[grow * 512 + gcol];
                crv[mt][v] = (float)Cprev[grow * 512 + 256 + gcol];
            }
#pragma unroll
        for (int mt = 0; mt < 4; mt++) {
#pragma unroll
            for (int v = 0; v < 4; v++) {
                long grow = wrow + mt * 16 + q * 4 + v;
                const float* xp = xg + idv[mt][v] * 256 + gcol;
                float fl = sigf(acc[0][mt][v] + xp[0]);          // f_l,f_r share xg[0]
                float fr = sigf(acc[1][mt][v] + xp[0]);
                float ig = sigf(acc[2][mt][v] + xp[16384]);      // xg[1]
                float og = sigf(acc[3][mt][v] + xp[32768]);      // xg[2]
                float ug = tanhfast(acc[4][mt][v] + xp[49152]);  // xg[3]
                float cv = ig * ug + fl * clv[mt][v] + fr * crv[mt][v];
                float hv = og * tanhfast(cv);
                h_out[grow * 256 + gcol] = (__bf16)hv;
                c_out[grow * 256 + gcol] = (__bf16)cv;
                if (rh_out) rh_out[grow * 256 + gcol] = hv;
            }
        }
    }
}

__global__ void scores_kernel(const float* __restrict__ rh, const float* __restrict__ Ws,
                              const float* __restrict__ bs, float* __restrict__ out) {
    int b = blockIdx.x;
    int t = threadIdx.x >> 6, lane = threadIdx.x & 63;
    float s = 0.f;
    for (int i = lane; i < 512; i += 64) s += rh[b * 512 + i] * Ws[i * 3 + t];
    for (int o = 32; o > 0; o >>= 1) s += __shfl_down(s, o);
    if (lane == 0) out[b * 3 + t] = s + bs[t];
}

extern "C" void kernel_launch(void* const* d_in, const int* in_sizes, int n_in,
                              void* d_out, int out_size, void* d_ws, size_t ws_size,
                              hipStream_t stream) {
    const int*   ids = (const int*)  d_in[0];
    const float* emb = (const float*)d_in[1];
    const float* W   = (const float*)d_in[2];
    const float* bW  = (const float*)d_in[3];
    const float* U   = (const float*)d_in[4];
    const float* Ws  = (const float*)d_in[5];
    const float* bs  = (const float*)d_in[6];
    float* out = (float*)d_out;   // [0:192) scores, [192:) root_hidden (64x512)

    char* ws = (char*)d_ws;
    float*  xg  = (float*)ws;                   //   262144 B : xg_table[4][64][256]
    __bf16* BtP = (__bf16*)(ws + 262144);       //  1310720 B : packed B fragments
    __bf16* h0  = (__bf16*)(ws + 1572864);      // 33554432 B : h ping (leaf-sized)
    __bf16* c0  = (__bf16*)(ws + 35127296);     // 33554432 B
    __bf16* h1  = (__bf16*)(ws + 68681728);     // 16777216 B : h pong
    __bf16* c1  = (__bf16*)(ws + 85458944);     // 16777216 B   (total 102236160 B)

    xg_prep<<<dim3(256), dim3(256), 0, stream>>>(emb, W, bW, xg);
    bt_prep<<<dim3(320), dim3(256), 0, stream>>>(U, BtP);
    leaf_kernel<<<dim3(2048), dim3(256), 0, stream>>>(ids, xg, h0, c0);

    __bf16* hb[2] = {h0, h1};
    __bf16* cb[2] = {c0, c1};
    int cur = 0;
    for (int lev = 9; lev >= 1; lev--) {
        int M = 64 << lev;                      // B * 2^lev rows
        int gx = (M + 511) / 512;
        float* rh = (lev == 1) ? (out + 192) : nullptr;
        level_kernel<<<dim3(gx, 16), dim3(512), 0, stream>>>(
            hb[cur], cb[cur], BtP, xg, ids, hb[1 - cur], cb[1 - cur], rh, lev, M);
        cur = 1 - cur;
    }
    scores_kernel<<<dim3(64), dim3(192), 0, stream>>>(out + 192, Ws, bs, out);
}

// Round 8
// 449.505 us; speedup vs baseline: 1.0639x; 1.0639x over previous
//
#include <hip/hip_runtime.h>
#include <hip/hip_bf16.h>
#include <stdint.h>
#include <math.h>

// TreeLSTM on MI355X — v8: v5's measured body + XCD-affine ct-fast dispatch
// swizzle. All 16 col-tile blocks of a row-group run consecutively on ONE XCD
// -> active A (2MB) + B (1.25MB) fit that XCD's 4MB L2; A's 16x reuse becomes
// L2 hits; stores of the same rows merge into full lines.

typedef __bf16 bf16x8 __attribute__((ext_vector_type(8)));
typedef float  f32x4  __attribute__((ext_vector_type(4)));
typedef int    i32x4  __attribute__((ext_vector_type(4)));

__device__ __forceinline__ float sigf(float x) { return 1.f / (1.f + __expf(-x)); }
__device__ __forceinline__ float tanhfast(float x) {
    return 1.f - 2.f / (__expf(2.f * x) + 1.f);   // stable at |x| large
}

__global__ void xg_prep(const float* __restrict__ emb, const float* __restrict__ W,
                        const float* __restrict__ bW, float* __restrict__ xg) {
    int g = blockIdx.x >> 6, v = blockIdx.x & 63, k = threadIdx.x;
    __shared__ float e[256];
    e[k] = emb[v * 256 + k];
    __syncthreads();
    float s = bW[g * 256 + k];
    const float* Wg = W + g * 65536 + k;
#pragma unroll 4
    for (int i = 0; i < 256; i++) s += e[i] * Wg[i * 256];
    xg[(g * 64 + v) * 256 + k] = s;
}

// Pack U into MFMA-fragment order: BtP[g][ct][ks][lane][e], e<8
// value = Ucat[g][col=ct*16+(lane&15)][k=ks*32+(lane>>4)*8+e]
// Ucat[g][col][k] = U[g][k<256?0:1][k&255][col]
__global__ void bt_prep(const float* __restrict__ U, __bf16* __restrict__ BtP) {
    int t = blockIdx.x * 256 + threadIdx.x;     // < 81920
    int g    = t >> 14;
    int r    = t & 16383;
    int ct   = r >> 10;
    int ks   = (r >> 6) & 15;
    int lane = t & 63;
    int lr = lane & 15, q = lane >> 4;
    int col = ct * 16 + lr;
    int kbase = ks * 32 + q * 8;
    bf16x8 v8;
#pragma unroll
    for (int e = 0; e < 8; e++) {
        int k = kbase + e;
        int s = k >> 8, kk = k & 255;
        v8[e] = (__bf16)U[((g * 2 + s) * 256 + kk) * 256 + col];
    }
    *(bf16x8*)(BtP + (long)t * 8) = v8;
}

__global__ void leaf_kernel(const int* __restrict__ ids, const float* __restrict__ xg,
                            __bf16* __restrict__ h, __bf16* __restrict__ c) {
    int col = threadIdx.x;                 // 0..255
    int r0 = blockIdx.x * 32;              // 2048 blocks x 32 rows
    for (int r = r0; r < r0 + 32; r++) {
        int b = r >> 10, j = r & 1023;
        int id = ids[b * 2046 + 1022 + j];
        float x1 = xg[(64  + id) * 256 + col];
        float x2 = xg[(128 + id) * 256 + col];
        float x3 = xg[(192 + id) * 256 + col];
        float ig = sigf(x1);
        float og = sigf(x2);
        float ug = tanhfast(x3);
        float cv = ig * ug;
        float hv = og * tanhfast(cv);
        h[r * 256 + col] = (__bf16)hv;
        c[r * 256 + col] = (__bf16)cv;
    }
}

// Block = 512 thr = 8 waves x 64 rows; one ct (16 cols), all 5 gates.
// 1-D grid of RG*16 blocks; decode (rg, ct) with XCD-affine ct-fast swizzle.
__global__ __launch_bounds__(512, 2) void level_kernel(
    const __bf16* __restrict__ A, const __bf16* __restrict__ Cprev,
    const __bf16* __restrict__ BtP, const float* __restrict__ xg,
    const int* __restrict__ ids, __bf16* __restrict__ h_out,
    __bf16* __restrict__ c_out, float* __restrict__ rh_out, int lev, int M, int RG) {
    __shared__ __bf16 Blds[5 * 16 * 512];     // 80 KB -> 2 blocks/CU
    const int gid = blockIdx.x;
    int rg, ct;
    if ((RG & 7) == 0) {
        // XCD-affine: 16 consecutive blocks on one XCD = one rowgroup's 16 cts.
        int xcd = gid & 7;
        int t   = gid >> 3;
        ct = t & 15;
        rg = ((t >> 4) << 3) | xcd;
    } else {
        rg = gid >> 4;
        ct = gid & 15;
    }
    const int tid  = threadIdx.x;
    const int wave = tid >> 6;
    const int lane = tid & 63;
    const int lr = lane & 15, q = lane >> 4;
    const long wrow = (long)rg * 512 + wave * 64;
    const bool active = (wrow < M);

    // ---- Stage B-slice -> LDS, fragment order (conflict-free 16B/lane). ----
#pragma unroll
    for (int i = 0; i < 10; i++) {
        int c = tid + i * 512;
        int g = c >> 10;
        int r = c & 1023;
        i32x4 v = *(const i32x4*)(BtP + (long)(g * 16 + ct) * 8192 + r * 8);
        *(i32x4*)(&Blds[g * 8192 + r * 8]) = v;
    }

    // ---- A prefetch: steps 0 and 1 (2-deep). ----
    const __bf16* Ap = A + (wrow + lr) * 512 + q * 8;   // + mt*8192 + s*32
    bf16x8 af[3][4];
    if (active) {
#pragma unroll
        for (int mt = 0; mt < 4; mt++) {
            af[0][mt] = *(const bf16x8*)(Ap + mt * 8192);
            af[1][mt] = *(const bf16x8*)(Ap + mt * 8192 + 32);
        }
    }

    __syncthreads();

    // ---- Preload ids and children's c (latency hides under the K-loop). ----
    const int n = 1 << lev;
    const int gcol = ct * 16 + lr;
    int idv[4][4];
    __bf16 clv[4][4], crv[4][4];
    if (active) {
#pragma unroll
        for (int mt = 0; mt < 4; mt++)
#pragma unroll
            for (int v = 0; v < 4; v++) {
                long grow = wrow + mt * 16 + q * 4 + v;
                int b = (int)(grow >> lev);
                int j = (int)(grow & (n - 1));
                idv[mt][v] = ids[b * 2046 + (n - 2) + j];
                clv[mt][v] = Cprev[grow * 512 + gcol];
                crv[mt][v] = Cprev[grow * 512 + 256 + gcol];
            }
    }

    if (active) {
        f32x4 acc[5][4];
#pragma unroll
        for (int g2 = 0; g2 < 5; g2++)
#pragma unroll
            for (int mt = 0; mt < 4; mt++) acc[g2][mt] = (f32x4){0.f, 0.f, 0.f, 0.f};

        // B double-buffer from LDS (ds_read_b128, conflict-free: lane*16B).
        bf16x8 bb[2][5];
#pragma unroll
        for (int g2 = 0; g2 < 5; g2++)
            bb[0][g2] = *(const bf16x8*)(&Blds[g2 * 8192 + lane * 8]);

#pragma unroll
        for (int s = 0; s < 16; s++) {
            if (s + 1 < 16) {
#pragma unroll
                for (int g2 = 0; g2 < 5; g2++)
                    bb[(s + 1) & 1][g2] =
                        *(const bf16x8*)(&Blds[g2 * 8192 + (s + 1) * 512 + lane * 8]);
            }
            if (s + 2 < 16) {
#pragma unroll
                for (int mt = 0; mt < 4; mt++)
                    af[(s + 2) % 3][mt] =
                        *(const bf16x8*)(Ap + mt * 8192 + (s + 2) * 32);
            }
#pragma unroll
            for (int g2 = 0; g2 < 5; g2++)
#pragma unroll
                for (int mt = 0; mt < 4; mt++)
                    acc[g2][mt] = __builtin_amdgcn_mfma_f32_16x16x32_bf16(
                        af[s % 3][mt], bb[s & 1][g2], acc[g2][mt], 0, 0, 0);
        }

        // ---- Epilogue: in-register gate combine. col=lane&15, row=q*4+v. ----
#pragma unroll
        for (int mt = 0; mt < 4; mt++) {
#pragma unroll
            for (int v = 0; v < 4; v++) {
                long grow = wrow + mt * 16 + q * 4 + v;
                const float* xp = xg + idv[mt][v] * 256 + gcol;
                float fl = sigf(acc[0][mt][v] + xp[0]);          // f_l,f_r share xg[0]
                float fr = sigf(acc[1][mt][v] + xp[0]);
                float ig = sigf(acc[2][mt][v] + xp[16384]);      // xg[1]
                float og = sigf(acc[3][mt][v] + xp[32768]);      // xg[2]
                float ug = tanhfast(acc[4][mt][v] + xp[49152]);  // xg[3]
                float cv = ig * ug + fl * (float)clv[mt][v] + fr * (float)crv[mt][v];
                float hv = og * tanhfast(cv);
                h_out[grow * 256 + gcol] = (__bf16)hv;
                c_out[grow * 256 + gcol] = (__bf16)cv;
                if (rh_out) rh_out[grow * 256 + gcol] = hv;
            }
        }
    }
}

__global__ void scores_kernel(const float* __restrict__ rh, const float* __restrict__ Ws,
                              const float* __restrict__ bs, float* __restrict__ out) {
    int b = blockIdx.x;
    int t = threadIdx.x >> 6, lane = threadIdx.x & 63;
    float s = 0.f;
    for (int i = lane; i < 512; i += 64) s += rh[b * 512 + i] * Ws[i * 3 + t];
    for (int o = 32; o > 0; o >>= 1) s += __shfl_down(s, o);
    if (lane == 0) out[b * 3 + t] = s + bs[t];
}

extern "C" void kernel_launch(void* const* d_in, const int* in_sizes, int n_in,
                              void* d_out, int out_size, void* d_ws, size_t ws_size,
                              hipStream_t stream) {
    const int*   ids = (const int*)  d_in[0];
    const float* emb = (const float*)d_in[1];
    const float* W   = (const float*)d_in[2];
    const float* bW  = (const float*)d_in[3];
    const float* U   = (const float*)d_in[4];
    const float* Ws  = (const float*)d_in[5];
    const float* bs  = (const float*)d_in[6];
    float* out = (float*)d_out;   // [0:192) scores, [192:) root_hidden (64x512)

    char* ws = (char*)d_ws;
    float*  xg  = (float*)ws;                   //   262144 B : xg_table[4][64][256]
    __bf16* BtP = (__bf16*)(ws + 262144);       //  1310720 B : packed B fragments
    __bf16* h0  = (__bf16*)(ws + 1572864);      // 33554432 B : h ping (leaf-sized)
    __bf16* c0  = (__bf16*)(ws + 35127296);     // 33554432 B
    __bf16* h1  = (__bf16*)(ws + 68681728);     // 16777216 B : h pong
    __bf16* c1  = (__bf16*)(ws + 85458944);     // 16777216 B   (total 102236160 B)

    xg_prep<<<dim3(256), dim3(256), 0, stream>>>(emb, W, bW, xg);
    bt_prep<<<dim3(320), dim3(256), 0, stream>>>(U, BtP);
    leaf_kernel<<<dim3(2048), dim3(256), 0, stream>>>(ids, xg, h0, c0);

    __bf16* hb[2] = {h0, h1};
    __bf16* cb[2] = {c0, c1};
    int cur = 0;
    for (int lev = 9; lev >= 1; lev--) {
        int M = 64 << lev;                      // B * 2^lev rows
        int RG = (M + 511) / 512;
        float* rh = (lev == 1) ? (out + 192) : nullptr;
        level_kernel<<<dim3(RG * 16), dim3(512), 0, stream>>>(
            hb[cur], cb[cur], BtP, xg, ids, hb[1 - cur], cb[1 - cur], rh, lev, M, RG);
        cur = 1 - cur;
    }
    scores_kernel<<<dim3(64), dim3(192), 0, stream>>>(out + 192, Ws, bs, out);
}